// Round 2
// baseline (48045.868 us; speedup 1.0000x reference)
//
#include <hip/hip_runtime.h>

#define NROWS    32
#define HID      512
#define DXD      256
#define DYD      64
#define LRC      0.1f
#define NTHREADS 256
// LDS: c[32][512] + abuf[32][512] + y[32][64] floats, + t[32] ints
#define SMEM_BYTES ((2*NROWS*HID + NROWS*DYD)*4 + NROWS*4)

__global__ __launch_bounds__(NTHREADS, 1)
void ebm_steps(const float* __restrict__ x, const int* __restrict__ tt,
               const float* __restrict__ W1, const float* __restrict__ b1,
               const float* __restrict__ W2, const float* __restrict__ b2,
               const float* __restrict__ W3, const int* __restrict__ stepsp,
               float* __restrict__ out)
{
    extern __shared__ float smem[];
    float* cbuf = smem;                    // [32][512] step-invariant x@W1x+b1
    float* abuf = smem + NROWS*HID;        // [32][512] h1 -> m2 -> m1 (reused)
    float* ybuf = abuf + NROWS*HID;        // [32][64]
    int*   tl   = (int*)(ybuf + NROWS*DYD);// [32]

    const int tid = threadIdx.x;
    const int r0  = blockIdx.x * NROWS;
    const int nsteps = *stepsp;

    for (int i = tid; i < NROWS*DYD; i += NTHREADS) ybuf[i] = 0.0f;
    if (tid < NROWS) {
        int tv = tt[r0 + tid];
        tl[tid] = tv < 0 ? 0 : tv;
    }
    // stage x tile into abuf packed [32][256]
    {
        const float4* xs = (const float4*)(x + (size_t)r0 * DXD);
        float4* xd = (float4*)abuf;
        for (int i = tid; i < NROWS*DXD/4; i += NTHREADS) xd[i] = xs[i];
    }
    __syncthreads();

    const int h0 = tid, h1 = tid + NTHREADS;   // the 2 hidden columns this thread owns

    float acc0[NROWS], acc1[NROWS];

    // c = x @ W1[:256] + b1   (coalesced W1 column reads across lanes)
    {
        float bb0 = b1[h0], bb1 = b1[h1];
        #pragma unroll
        for (int r = 0; r < NROWS; ++r) { acc0[r] = bb0; acc1[r] = bb1; }
        for (int i = 0; i < DXD; i += 4) {
            float wa0 = W1[(i+0)*HID + h0], wb0 = W1[(i+0)*HID + h1];
            float wa1 = W1[(i+1)*HID + h0], wb1 = W1[(i+1)*HID + h1];
            float wa2 = W1[(i+2)*HID + h0], wb2 = W1[(i+2)*HID + h1];
            float wa3 = W1[(i+3)*HID + h0], wb3 = W1[(i+3)*HID + h1];
            #pragma unroll
            for (int r = 0; r < NROWS; ++r) {
                float4 xv = *(const float4*)&abuf[r*DXD + i];   // wave-uniform broadcast
                acc0[r] = fmaf(xv.x, wa0, acc0[r]); acc1[r] = fmaf(xv.x, wb0, acc1[r]);
                acc0[r] = fmaf(xv.y, wa1, acc0[r]); acc1[r] = fmaf(xv.y, wb1, acc1[r]);
                acc0[r] = fmaf(xv.z, wa2, acc0[r]); acc1[r] = fmaf(xv.z, wb2, acc1[r]);
                acc0[r] = fmaf(xv.w, wa3, acc0[r]); acc1[r] = fmaf(xv.w, wb3, acc1[r]);
            }
        }
        #pragma unroll
        for (int r = 0; r < NROWS; ++r) {
            cbuf[r*HID + h0] = acc0[r];
            cbuf[r*HID + h1] = acc1[r];
        }
    }

    unsigned mA = 0u, mB = 0u;   // relu masks (bit per row) for this thread's 2 columns

    for (int s = 0; s < nsteps; ++s) {
        __syncthreads();  // prev-step abuf reads + y writes complete

        // ---- stage 1: a1 = c + y @ W1y ; h1 = relu(a1) -> abuf; record masks
        #pragma unroll
        for (int r = 0; r < NROWS; ++r) { acc0[r] = cbuf[r*HID + h0]; acc1[r] = cbuf[r*HID + h1]; }
        for (int d = 0; d < DYD; d += 4) {
            float wa0 = W1[(DXD+d+0)*HID + h0], wb0 = W1[(DXD+d+0)*HID + h1];
            float wa1 = W1[(DXD+d+1)*HID + h0], wb1 = W1[(DXD+d+1)*HID + h1];
            float wa2 = W1[(DXD+d+2)*HID + h0], wb2 = W1[(DXD+d+2)*HID + h1];
            float wa3 = W1[(DXD+d+3)*HID + h0], wb3 = W1[(DXD+d+3)*HID + h1];
            #pragma unroll
            for (int r = 0; r < NROWS; ++r) {
                float4 yv = *(const float4*)&ybuf[r*DYD + d];
                acc0[r] = fmaf(yv.x, wa0, acc0[r]); acc1[r] = fmaf(yv.x, wb0, acc1[r]);
                acc0[r] = fmaf(yv.y, wa1, acc0[r]); acc1[r] = fmaf(yv.y, wb1, acc1[r]);
                acc0[r] = fmaf(yv.z, wa2, acc0[r]); acc1[r] = fmaf(yv.z, wb2, acc1[r]);
                acc0[r] = fmaf(yv.w, wa3, acc0[r]); acc1[r] = fmaf(yv.w, wb3, acc1[r]);
            }
        }
        mA = 0u; mB = 0u;
        #pragma unroll
        for (int r = 0; r < NROWS; ++r) {
            mA |= (acc0[r] > 0.0f ? (1u << r) : 0u);
            mB |= (acc1[r] > 0.0f ? (1u << r) : 0u);
            abuf[r*HID + h0] = fmaxf(acc0[r], 0.0f);
            abuf[r*HID + h1] = fmaxf(acc1[r], 0.0f);
        }
        __syncthreads();

        // ---- stage 2: a2 = h1 @ W2 + b2 (regs), then m2 = (a2>0)?W3[:,t]:0 -> abuf
        {
            float bb0 = b2[h0], bb1 = b2[h1];
            #pragma unroll
            for (int r = 0; r < NROWS; ++r) { acc0[r] = bb0; acc1[r] = bb1; }
        }
        for (int k = 0; k < HID; k += 4) {
            float wa0 = W2[(k+0)*HID + h0], wb0 = W2[(k+0)*HID + h1];
            float wa1 = W2[(k+1)*HID + h0], wb1 = W2[(k+1)*HID + h1];
            float wa2 = W2[(k+2)*HID + h0], wb2 = W2[(k+2)*HID + h1];
            float wa3 = W2[(k+3)*HID + h0], wb3 = W2[(k+3)*HID + h1];
            #pragma unroll
            for (int r = 0; r < NROWS; ++r) {
                float4 hv = *(const float4*)&abuf[r*HID + k];   // broadcast
                acc0[r] = fmaf(hv.x, wa0, acc0[r]); acc1[r] = fmaf(hv.x, wb0, acc1[r]);
                acc0[r] = fmaf(hv.y, wa1, acc0[r]); acc1[r] = fmaf(hv.y, wb1, acc1[r]);
                acc0[r] = fmaf(hv.z, wa2, acc0[r]); acc1[r] = fmaf(hv.z, wb2, acc1[r]);
                acc0[r] = fmaf(hv.w, wa3, acc0[r]); acc1[r] = fmaf(hv.w, wb3, acc1[r]);
            }
        }
        __syncthreads();   // all h1 reads done before overwrite
        #pragma unroll
        for (int r = 0; r < NROWS; ++r) {
            int tv = tl[r];
            abuf[r*HID + h0] = (acc0[r] > 0.0f) ? W3[h0*4 + tv] : 0.0f;
            abuf[r*HID + h1] = (acc1[r] > 0.0f) ? W3[h1*4 + tv] : 0.0f;
        }
        __syncthreads();

        // ---- stage 3: g2 = m2 @ W2^T (regs), then m1 = g2 * mask1 -> abuf
        #pragma unroll
        for (int r = 0; r < NROWS; ++r) { acc0[r] = 0.0f; acc1[r] = 0.0f; }
        for (int k = 0; k < HID; k += 4) {
            float4 w0 = *(const float4*)&W2[(size_t)h0*HID + k];  // contiguous per lane
            float4 w1 = *(const float4*)&W2[(size_t)h1*HID + k];
            #pragma unroll
            for (int r = 0; r < NROWS; ++r) {
                float4 mv = *(const float4*)&abuf[r*HID + k];   // broadcast
                acc0[r] = fmaf(mv.x, w0.x, acc0[r]); acc1[r] = fmaf(mv.x, w1.x, acc1[r]);
                acc0[r] = fmaf(mv.y, w0.y, acc0[r]); acc1[r] = fmaf(mv.y, w1.y, acc1[r]);
                acc0[r] = fmaf(mv.z, w0.z, acc0[r]); acc1[r] = fmaf(mv.z, w1.z, acc1[r]);
                acc0[r] = fmaf(mv.w, w0.w, acc0[r]); acc1[r] = fmaf(mv.w, w1.w, acc1[r]);
            }
        }
        __syncthreads();   // all m2 reads done
        #pragma unroll
        for (int r = 0; r < NROWS; ++r) {
            abuf[r*HID + h0] = ((mA >> r) & 1u) ? acc0[r] : 0.0f;
            abuf[r*HID + h1] = ((mB >> r) & 1u) ? acc1[r] : 0.0f;
        }
        __syncthreads();

        // ---- stage 4: grad_y[r][d] = sum_j m1[r][j] * W1[256+d][j]; y -= LR*grad
        {
            const int d  = tid & 63;
            const int rg = tid >> 6;               // wave id -> row group (uniform per wave)
            float gacc[8];
            #pragma unroll
            for (int q = 0; q < 8; ++q) gacc[q] = 0.0f;
            const float* w1row = &W1[(size_t)(DXD + d) * HID];
            for (int j = 0; j < HID; j += 4) {
                float4 wv = *(const float4*)&w1row[j];          // contiguous per lane
                #pragma unroll
                for (int q = 0; q < 8; ++q) {
                    const int r = rg*8 + q;
                    float4 mv = *(const float4*)&abuf[r*HID + j]; // broadcast
                    gacc[q] = fmaf(mv.x, wv.x, gacc[q]);
                    gacc[q] = fmaf(mv.y, wv.y, gacc[q]);
                    gacc[q] = fmaf(mv.z, wv.z, gacc[q]);
                    gacc[q] = fmaf(mv.w, wv.w, gacc[q]);
                }
            }
            #pragma unroll
            for (int q = 0; q < 8; ++q) {
                const int r = rg*8 + q;
                ybuf[r*DYD + d] -= LRC * gacc[q];
            }
        }
    }

    __syncthreads();
    {
        const float4* ys = (const float4*)ybuf;
        float4* od = (float4*)(out + (size_t)r0 * DYD);
        for (int i = tid; i < NROWS*DYD/4; i += NTHREADS) od[i] = ys[i];
    }
}

extern "C" void kernel_launch(void* const* d_in, const int* in_sizes, int n_in,
                              void* d_out, int out_size, void* d_ws, size_t ws_size,
                              hipStream_t stream) {
    const float* x  = (const float*)d_in[0];
    const int*   t  = (const int*)d_in[1];
    const float* W1 = (const float*)d_in[2];
    const float* b1 = (const float*)d_in[3];
    const float* W2 = (const float*)d_in[4];
    const float* b2 = (const float*)d_in[5];
    const float* W3 = (const float*)d_in[6];
    // d_in[7] = b3: constant offset, no effect on grad_y
    const int* steps = (const int*)d_in[8];
    float* out = (float*)d_out;

    const int B = in_sizes[0] / DXD;
    const int nblocks = B / NROWS;

    (void)hipFuncSetAttribute((const void*)ebm_steps,
                              hipFuncAttributeMaxDynamicSharedMemorySize,
                              SMEM_BYTES);
    ebm_steps<<<nblocks, NTHREADS, SMEM_BYTES, stream>>>(x, t, W1, b1, W2, b2, W3, steps, out);
}

// Round 6
// 33445.108 us; speedup vs baseline: 1.4366x; 1.4366x over previous
//
#include <hip/hip_runtime.h>

#define NROWS    16
#define HID      512
#define DXD      256
#define DYD      64
#define LRC      0.1f
#define NTHREADS 512
// LDS: c[16][512] + abuf[16][512] + y[16][64] floats, + t[16] ints (padded)
#define SMEM_BYTES ((2*NROWS*HID + NROWS*DYD)*4 + 64)

__global__ __launch_bounds__(NTHREADS, 4)
void ebm_steps(const float* __restrict__ x, const int* __restrict__ tt,
               const float* __restrict__ W1, const float* __restrict__ b1,
               const float* __restrict__ W2, const float* __restrict__ b2,
               const float* __restrict__ W3, const int* __restrict__ stepsp,
               float* __restrict__ out)
{
    extern __shared__ float smem[];
    float* cbuf = smem;                    // [16][512] step-invariant x@W1x+b1
    float* abuf = smem + NROWS*HID;        // [16][512] h1 -> m2 -> m1 (reused)
    float* ybuf = abuf + NROWS*HID;        // [16][64]
    int*   tl   = (int*)(ybuf + NROWS*DYD);// [16]

    const int tid = threadIdx.x;
    const int r0  = blockIdx.x * NROWS;
    const int nsteps = *stepsp;

    for (int i = tid; i < NROWS*DYD; i += NTHREADS) ybuf[i] = 0.0f;
    if (tid < NROWS) {
        int tv = tt[r0 + tid];
        tl[tid] = tv < 0 ? 0 : tv;
    }
    // stage x tile into abuf packed [16][256]
    {
        const float4* xs = (const float4*)(x + (size_t)r0 * DXD);
        float4* xd = (float4*)abuf;
        for (int i = tid; i < NROWS*DXD/4; i += NTHREADS) xd[i] = xs[i];
    }
    __syncthreads();

    const int h0 = tid;                // the hidden column this thread owns

    float acc0[NROWS];

    // c = x @ W1[:256] + b1   (same per-element fmaf chain as the passing r2 kernel)
    {
        float bb0 = b1[h0];
        #pragma unroll
        for (int r = 0; r < NROWS; ++r) acc0[r] = bb0;
        for (int i = 0; i < DXD; i += 4) {
            float wa0 = W1[(i+0)*HID + h0];
            float wa1 = W1[(i+1)*HID + h0];
            float wa2 = W1[(i+2)*HID + h0];
            float wa3 = W1[(i+3)*HID + h0];
            #pragma unroll
            for (int r = 0; r < NROWS; ++r) {
                float4 xv = *(const float4*)&abuf[r*DXD + i];   // wave-uniform broadcast
                acc0[r] = fmaf(xv.x, wa0, acc0[r]);
                acc0[r] = fmaf(xv.y, wa1, acc0[r]);
                acc0[r] = fmaf(xv.z, wa2, acc0[r]);
                acc0[r] = fmaf(xv.w, wa3, acc0[r]);
            }
        }
        #pragma unroll
        for (int r = 0; r < NROWS; ++r) cbuf[r*HID + h0] = acc0[r];
    }

    unsigned mA = 0u;   // relu mask (bit per row) for this thread's column

    for (int s = 0; s < nsteps; ++s) {
        __syncthreads();  // prev-step abuf reads + y writes complete

        // ---- stage 1: a1 = c + y @ W1y ; h1 = relu(a1) -> abuf; record masks
        #pragma unroll
        for (int r = 0; r < NROWS; ++r) acc0[r] = cbuf[r*HID + h0];
        for (int d = 0; d < DYD; d += 4) {
            float wa0 = W1[(DXD+d+0)*HID + h0];
            float wa1 = W1[(DXD+d+1)*HID + h0];
            float wa2 = W1[(DXD+d+2)*HID + h0];
            float wa3 = W1[(DXD+d+3)*HID + h0];
            #pragma unroll
            for (int r = 0; r < NROWS; ++r) {
                float4 yv = *(const float4*)&ybuf[r*DYD + d];
                acc0[r] = fmaf(yv.x, wa0, acc0[r]);
                acc0[r] = fmaf(yv.y, wa1, acc0[r]);
                acc0[r] = fmaf(yv.z, wa2, acc0[r]);
                acc0[r] = fmaf(yv.w, wa3, acc0[r]);
            }
        }
        mA = 0u;
        #pragma unroll
        for (int r = 0; r < NROWS; ++r) {
            mA |= (acc0[r] > 0.0f ? (1u << r) : 0u);
            abuf[r*HID + h0] = fmaxf(acc0[r], 0.0f);
        }
        __syncthreads();

        // ---- stage 2: a2 = h1 @ W2 + b2 (regs), then m2 = (a2>0)?W3[:,t]:0 -> abuf
        {
            float bb0 = b2[h0];
            #pragma unroll
            for (int r = 0; r < NROWS; ++r) acc0[r] = bb0;
        }
        for (int k = 0; k < HID; k += 4) {
            float wa0 = W2[(k+0)*HID + h0];
            float wa1 = W2[(k+1)*HID + h0];
            float wa2 = W2[(k+2)*HID + h0];
            float wa3 = W2[(k+3)*HID + h0];
            #pragma unroll
            for (int r = 0; r < NROWS; ++r) {
                float4 hv = *(const float4*)&abuf[r*HID + k];   // broadcast
                acc0[r] = fmaf(hv.x, wa0, acc0[r]);
                acc0[r] = fmaf(hv.y, wa1, acc0[r]);
                acc0[r] = fmaf(hv.z, wa2, acc0[r]);
                acc0[r] = fmaf(hv.w, wa3, acc0[r]);
            }
        }
        __syncthreads();   // all h1 reads done before overwrite
        #pragma unroll
        for (int r = 0; r < NROWS; ++r) {
            int tv = tl[r];
            abuf[r*HID + h0] = (acc0[r] > 0.0f) ? W3[h0*4 + tv] : 0.0f;
        }
        __syncthreads();

        // ---- stage 3: g2 = m2 @ W2^T (regs), then m1 = g2 * mask1 -> abuf
        #pragma unroll
        for (int r = 0; r < NROWS; ++r) acc0[r] = 0.0f;
        for (int k = 0; k < HID; k += 4) {
            float4 w0 = *(const float4*)&W2[(size_t)h0*HID + k];  // contiguous per lane
            #pragma unroll
            for (int r = 0; r < NROWS; ++r) {
                float4 mv = *(const float4*)&abuf[r*HID + k];   // broadcast
                acc0[r] = fmaf(mv.x, w0.x, acc0[r]);
                acc0[r] = fmaf(mv.y, w0.y, acc0[r]);
                acc0[r] = fmaf(mv.z, w0.z, acc0[r]);
                acc0[r] = fmaf(mv.w, w0.w, acc0[r]);
            }
        }
        __syncthreads();   // all m2 reads done
        #pragma unroll
        for (int r = 0; r < NROWS; ++r) {
            abuf[r*HID + h0] = ((mA >> r) & 1u) ? acc0[r] : 0.0f;
        }
        __syncthreads();

        // ---- stage 4: grad_y[r][d] = sum_j m1[r][j] * W1[256+d][j]; y -= LR*grad
        {
            const int d  = tid & 63;
            const int rg = tid >> 6;               // wave id -> row group (uniform per wave)
            float gacc[2];
            gacc[0] = 0.0f; gacc[1] = 0.0f;
            const float* w1row = &W1[(size_t)(DXD + d) * HID];
            for (int j = 0; j < HID; j += 4) {
                float4 wv = *(const float4*)&w1row[j];          // contiguous per lane
                #pragma unroll
                for (int q = 0; q < 2; ++q) {
                    const int r = rg*2 + q;
                    float4 mv = *(const float4*)&abuf[r*HID + j]; // broadcast
                    gacc[q] = fmaf(mv.x, wv.x, gacc[q]);
                    gacc[q] = fmaf(mv.y, wv.y, gacc[q]);
                    gacc[q] = fmaf(mv.z, wv.z, gacc[q]);
                    gacc[q] = fmaf(mv.w, wv.w, gacc[q]);
                }
            }
            #pragma unroll
            for (int q = 0; q < 2; ++q) {
                const int r = rg*2 + q;
                ybuf[r*DYD + d] -= LRC * gacc[q];
            }
        }
    }

    __syncthreads();
    {
        const float4* ys = (const float4*)ybuf;
        float4* od = (float4*)(out + (size_t)r0 * DYD);
        for (int i = tid; i < NROWS*DYD/4; i += NTHREADS) od[i] = ys[i];
    }
}

extern "C" void kernel_launch(void* const* d_in, const int* in_sizes, int n_in,
                              void* d_out, int out_size, void* d_ws, size_t ws_size,
                              hipStream_t stream) {
    const float* x  = (const float*)d_in[0];
    const int*   t  = (const int*)d_in[1];
    const float* W1 = (const float*)d_in[2];
    const float* b1 = (const float*)d_in[3];
    const float* W2 = (const float*)d_in[4];
    const float* b2 = (const float*)d_in[5];
    const float* W3 = (const float*)d_in[6];
    // d_in[7] = b3: constant offset, no effect on grad_y
    const int* steps = (const int*)d_in[8];
    float* out = (float*)d_out;

    const int B = in_sizes[0] / DXD;
    const int nblocks = B / NROWS;

    (void)hipFuncSetAttribute((const void*)ebm_steps,
                              hipFuncAttributeMaxDynamicSharedMemorySize,
                              SMEM_BYTES);
    ebm_steps<<<nblocks, NTHREADS, SMEM_BYTES, stream>>>(x, t, W1, b1, W2, b2, W3, steps, out);
}